// Round 1
// baseline (220.063 us; speedup 1.0000x reference)
//
#include <hip/hip_runtime.h>

#define BB 32
#define TT 36
#define NN 10000
#define FF 3
#define HH 10
#define RR 20

// ws layout (floats):
//   [0, BB*NN)                 : time_mean (NaN where node all-NaN)
//   [BB*NN, +BB*RR)            : per-(b,region) sum
//   [.., +BB*RR)               : per-(b,region) count
//   [.., +1)                   : global sum
//   [.., +1)                   : global count
//   [.., +1)                   : g1 (global nanmean of pred_speed)

__global__ void k_time_mean(const float* __restrict__ seq,
                            const int* __restrict__ cid,
                            float* __restrict__ tm,
                            float* __restrict__ rsum,
                            float* __restrict__ rcnt,
                            float* __restrict__ gsum,
                            float* __restrict__ gcnt) {
    __shared__ float ls[RR];
    __shared__ float lc[RR];
    __shared__ float lgs, lgc;
    const int b = blockIdx.y;
    const int n = blockIdx.x * blockDim.x + threadIdx.x;
    if (threadIdx.x < RR) { ls[threadIdx.x] = 0.f; lc[threadIdx.x] = 0.f; }
    if (threadIdx.x == RR)     lgs = 0.f;
    if (threadIdx.x == RR + 1) lgc = 0.f;
    __syncthreads();

    if (n < NN) {
        const float* p = seq + ((size_t)b * TT * NN + n) * FF;
        float s = 0.f;
        int c = 0;
        #pragma unroll
        for (int t = 0; t < TT; ++t) {
            float v = p[(size_t)t * NN * FF];
            if (v == v) { s += v; c++; }   // NaN-aware
        }
        float m = (c > 0) ? (s / (float)c) : __int_as_float(0x7fc00000);
        tm[b * NN + n] = m;
        if (c > 0) {
            int r = cid[n];
            atomicAdd(&ls[r], m);
            atomicAdd(&lc[r], 1.f);
            atomicAdd(&lgs, m);
            atomicAdd(&lgc, 1.f);
        }
    }
    __syncthreads();

    if (threadIdx.x < RR) {
        atomicAdd(&rsum[b * RR + threadIdx.x], ls[threadIdx.x]);
        atomicAdd(&rcnt[b * RR + threadIdx.x], lc[threadIdx.x]);
    } else if (threadIdx.x == RR) {
        atomicAdd(gsum, lgs);
    } else if (threadIdx.x == RR + 1) {
        atomicAdd(gcnt, lgc);
    }
}

// single block, 640 threads (B*R = 640 = 10 waves)
__global__ void k_regional(const float* __restrict__ rsum,
                           const float* __restrict__ rcnt,
                           const float* __restrict__ gsum,
                           const float* __restrict__ gcnt,
                           float* __restrict__ g1out,
                           float* __restrict__ out_reg) {
    const int tid = threadIdx.x;
    __shared__ float ssum[10];
    __shared__ float scnt[10];
    __shared__ float g2s;

    float val = 0.f;
    int valid = 0;
    if (tid < BB * RR) {
        float c = rcnt[tid];
        if (c > 0.f) { val = rsum[tid] / c; valid = 1; }
    }

    // wave(64) butterfly-free down-reduce
    float wsv = valid ? val : 0.f;
    float wcv = (float)valid;
    for (int off = 32; off > 0; off >>= 1) {
        wsv += __shfl_down(wsv, off, 64);
        wcv += __shfl_down(wcv, off, 64);
    }
    const int wave = tid >> 6;
    if ((tid & 63) == 0) { ssum[wave] = wsv; scnt[wave] = wcv; }
    __syncthreads();

    if (tid == 0) {
        float s = 0.f, c = 0.f;
        #pragma unroll
        for (int i = 0; i < 10; ++i) { s += ssum[i]; c += scnt[i]; }
        g2s = s / c;                 // g2: nanmean over regional entries
        g1out[0] = gsum[0] / gcnt[0]; // g1: nanmean over pred_speed entries
    }
    __syncthreads();

    if (tid < BB * RR) {
        const int b = tid / RR, r = tid % RR;
        const float o = valid ? val : g2s;
        #pragma unroll
        for (int h = 0; h < HH; ++h)
            out_reg[(size_t)(b * HH + h) * RR + r] = o;
    }
}

__global__ void k_pred(const float* __restrict__ tm,
                       const float* __restrict__ g1p,
                       float* __restrict__ out) {
    const int b = blockIdx.y;
    const int n = blockIdx.x * blockDim.x + threadIdx.x;
    if (n >= NN) return;
    const float g1 = g1p[0];
    float v = tm[b * NN + n];
    if (!(v == v)) v = g1;
    const size_t base = (size_t)b * HH * NN + n;
    #pragma unroll
    for (int h = 0; h < HH; ++h)
        out[base + (size_t)h * NN] = v;
}

extern "C" void kernel_launch(void* const* d_in, const int* in_sizes, int n_in,
                              void* d_out, int out_size, void* d_ws, size_t ws_size,
                              hipStream_t stream) {
    const float* seq = (const float*)d_in[0];
    const int*   cid = (const int*)d_in[1];
    float* out = (float*)d_out;

    float* ws   = (float*)d_ws;
    float* tm   = ws;                     // BB*NN
    float* rsum = tm + BB * NN;           // BB*RR
    float* rcnt = rsum + BB * RR;         // BB*RR
    float* gsum = rcnt + BB * RR;         // 1
    float* gcnt = gsum + 1;               // 1
    float* g1   = gcnt + 1;               // 1

    // zero the atomic accumulators (ws is poisoned 0xAA before every launch)
    hipMemsetAsync(rsum, 0, (size_t)(2 * BB * RR + 2) * sizeof(float), stream);

    dim3 blk(256);
    dim3 grd((NN + 255) / 256, BB);
    k_time_mean<<<grd, blk, 0, stream>>>(seq, cid, tm, rsum, rcnt, gsum, gcnt);
    k_regional<<<1, 640, 0, stream>>>(rsum, rcnt, gsum, gcnt, g1,
                                      out + (size_t)BB * HH * NN);
    k_pred<<<grd, blk, 0, stream>>>(tm, g1, out);
}